// Round 3
// baseline (693.722 us; speedup 1.0000x reference)
//
#include <hip/hip_runtime.h>
#include <math.h>

// GCN: h0 = lrelu(Agg(x@W0)+b0); h1 = lrelu(Agg(h0@W1)+b1); out = sigmoid(h1[idx]@Wm+bm)
// Agg (sym-norm + self loops): agg[d] = dinv[d] * ( sum_{e:dst=d} h_s[src] + h_s[d] ),
// with h_s = h * dinv[row] (pre-scaled in GEMM epilogue).
// Edges counting-sorted by dst into CSR once per call -> atomic-free aggregation.
// GEMMs: lane=row, acc[64] cols/lane, W rows broadcast from SGPRs (uniform loads),
// x staged in per-wave private LDS (no barriers), K chunked by 16, double-buffered.

__device__ __forceinline__ float lrelu(float x) { return x > 0.0f ? x : 0.01f * x; }

// ---------- degree / CSR build ----------

__global__ void k_hist(const int* __restrict__ dst, int E, int* __restrict__ cnt) {
    int i = blockIdx.x * blockDim.x + threadIdx.x;
    if (i < E) atomicAdd(cnt + dst[i], 1);
}

__global__ void k_dinv(const int* __restrict__ cnt, float* __restrict__ dinv, int N) {
    int i = blockIdx.x * blockDim.x + threadIdx.x;
    if (i < N) dinv[i] = rsqrtf((float)cnt[i] + 1.0f);  // +1 self loop
}

// 1024 elements per block (256 thr x 4)
__global__ void k_blocksum(const int* __restrict__ cnt, int N, int* __restrict__ bsum) {
    __shared__ int sm[256];
    int b = blockIdx.x, t = threadIdx.x;
    int base = b * 1024 + t * 4;
    int s = 0;
#pragma unroll
    for (int i = 0; i < 4; ++i) { int j = base + i; if (j < N) s += cnt[j]; }
    sm[t] = s; __syncthreads();
    for (int off = 128; off > 0; off >>= 1) {
        if (t < off) sm[t] += sm[t + off];
        __syncthreads();
    }
    if (t == 0) bsum[b] = sm[0];
}

// parallel exclusive scan of bsum (nb <= 1024), one block
__global__ void k_scan_bsum(int* __restrict__ bsum, int nb, int* __restrict__ offN) {
    __shared__ int sm[1024];
    int t = threadIdx.x;
    int v = (t < nb) ? bsum[t] : 0;
    sm[t] = v; __syncthreads();
    for (int d = 1; d < 1024; d <<= 1) {
        int add = (t >= d) ? sm[t - d] : 0;
        __syncthreads();
        sm[t] += add;
        __syncthreads();
    }
    if (t < nb) bsum[t] = sm[t] - v;       // exclusive
    if (t == nb - 1) *offN = sm[t];        // total == E -> off[N]
}

__global__ void k_scan_block(const int* __restrict__ cnt, const int* __restrict__ bsum,
                             int* __restrict__ off, int N) {
    __shared__ int sm[256];
    int b = blockIdx.x, t = threadIdx.x;
    int base = b * 1024 + t * 4;
    int v[4];
#pragma unroll
    for (int i = 0; i < 4; ++i) { int j = base + i; v[i] = (j < N) ? cnt[j] : 0; }
    int tsum = v[0] + v[1] + v[2] + v[3];
    sm[t] = tsum; __syncthreads();
    for (int d = 1; d < 256; d <<= 1) {
        int val = (t >= d) ? sm[t - d] : 0;
        __syncthreads();
        sm[t] += val;
        __syncthreads();
    }
    int run = sm[t] - tsum + bsum[b];  // exclusive prefix for this thread
#pragma unroll
    for (int i = 0; i < 4; ++i) {
        int j = base + i;
        if (j < N) off[j] = run;
        run += v[i];
    }
}

__global__ void k_scatter(const int* __restrict__ src, const int* __restrict__ dst,
                          const int* __restrict__ off, int* __restrict__ cnt,
                          int* __restrict__ esorted, int E) {
    int e = blockIdx.x * blockDim.x + threadIdx.x;
    if (e < E) {
        int d = dst[e];
        int p = off[d] + atomicAdd(cnt + d, 1);
        esorted[p] = src[e];
    }
}

// ---------- GEMMs ----------
// Wave handles 64 rows (lane=row). acc[64] = output row per lane.
// W row k is wave-uniform -> SGPR loads -> v_fmac(acc, s_w, v_x).
// x chunk (64 rows x 16 k) staged in per-wave LDS, row stride 17 (2-way bank alias = free).
// Double-buffered, no __syncthreads (LDS regions are wave-private).

template <int K, bool TRANS>  // TRANS: apply lrelu(v + b0[k]) while staging
__global__ __launch_bounds__(256) void k_gemm(const float* __restrict__ A,
                                              const float* __restrict__ W,
                                              const float* __restrict__ b0,
                                              const float* __restrict__ dinv,
                                              float* __restrict__ hout, int N) {
    constexpr int CH = 16, NCH = K / CH, STR = 17;
    __shared__ float xs[4 * 2 * 64 * STR];
    int lane = threadIdx.x & 63, wv = threadIdx.x >> 6;
    int rowBase = blockIdx.x * 256 + wv * 64;
    int row = rowBase + lane;
    float* my = xs + wv * (2 * 64 * STR);

    // staging regs for one chunk: 4 float4 per lane
    float4 st[4];

    auto load_chunk = [&](int c) {
#pragma unroll
        for (int j = 0; j < 4; ++j) {
            int g = j * 64 + lane;       // 0..255
            int r = g >> 2;              // tile row 0..63
            int kk4 = g & 3;             // float4 index within 16-k chunk
            int gr = rowBase + r; if (gr >= N) gr = N - 1;
            float4 v = *(const float4*)(A + (size_t)gr * K + c * CH + kk4 * 4);
            if (TRANS) {
                float4 b = *(const float4*)(b0 + c * CH + kk4 * 4);
                v.x = lrelu(v.x + b.x); v.y = lrelu(v.y + b.y);
                v.z = lrelu(v.z + b.z); v.w = lrelu(v.w + b.w);
            }
            st[j] = v;
        }
    };
    auto write_chunk = [&](int buf) {
#pragma unroll
        for (int j = 0; j < 4; ++j) {
            int g = j * 64 + lane;
            int r = g >> 2, kk4 = g & 3;
            float* p = my + buf * (64 * STR) + r * STR + kk4 * 4;
            p[0] = st[j].x; p[1] = st[j].y; p[2] = st[j].z; p[3] = st[j].w;
        }
    };

    float acc[64];
#pragma unroll
    for (int c = 0; c < 64; ++c) acc[c] = 0.0f;

    load_chunk(0);
    write_chunk(0);

    for (int c = 0; c < NCH; ++c) {
        if (c + 1 < NCH) load_chunk(c + 1);  // global loads overlap FMAs below
        const float* xb = my + (c & 1) * (64 * STR) + lane * STR;
#pragma unroll
        for (int kk = 0; kk < CH; ++kk) {
            float xv = xb[kk];
            const float4* W4 = (const float4*)(W + (size_t)(c * CH + kk) * 64);
#pragma unroll
            for (int cc = 0; cc < 16; ++cc) {
                float4 w = W4[cc];  // wave-uniform -> s_load
                acc[4 * cc + 0] = fmaf(xv, w.x, acc[4 * cc + 0]);
                acc[4 * cc + 1] = fmaf(xv, w.y, acc[4 * cc + 1]);
                acc[4 * cc + 2] = fmaf(xv, w.z, acc[4 * cc + 2]);
                acc[4 * cc + 3] = fmaf(xv, w.w, acc[4 * cc + 3]);
            }
        }
        if (c + 1 < NCH) write_chunk((c + 1) & 1);
    }

    if (row >= N) return;
    float dv = dinv[row];
    float* o = hout + (size_t)row * 64;
#pragma unroll
    for (int cc = 0; cc < 16; ++cc) {
        float4 v;
        v.x = acc[4 * cc + 0] * dv; v.y = acc[4 * cc + 1] * dv;
        v.z = acc[4 * cc + 2] * dv; v.w = acc[4 * cc + 3] * dv;
        *(float4*)(o + 4 * cc) = v;
    }
}

// ---------- CSR aggregation: one wave per node, lane = channel ----------

__global__ __launch_bounds__(256) void k_agg(const int* __restrict__ off,
                                             const int* __restrict__ esorted,
                                             const float* __restrict__ dinv,
                                             const float* __restrict__ hs,
                                             float* __restrict__ agg, int N) {
    int lane = threadIdx.x & 63;
    int node = (blockIdx.x * blockDim.x + threadIdx.x) >> 6;
    if (node >= N) return;
    int beg = off[node], end = off[node + 1];
    float acc = hs[(size_t)node * 64 + lane];  // self loop
    int j = beg;
    for (; j + 4 <= end; j += 4) {
        int s0 = esorted[j], s1 = esorted[j + 1], s2 = esorted[j + 2], s3 = esorted[j + 3];
        float v0 = hs[(size_t)s0 * 64 + lane];
        float v1 = hs[(size_t)s1 * 64 + lane];
        float v2 = hs[(size_t)s2 * 64 + lane];
        float v3 = hs[(size_t)s3 * 64 + lane];
        acc += (v0 + v1) + (v2 + v3);
    }
    for (; j < end; ++j) acc += hs[(size_t)esorted[j] * 64 + lane];
    agg[(size_t)node * 64 + lane] = acc * dinv[node];
}

// ---------- epilogue ----------

__global__ void k_out(const int* __restrict__ idx, const float* __restrict__ agg,
                      const float* __restrict__ b1, const float* __restrict__ Wm,
                      const float* __restrict__ bm, float* __restrict__ out, int NSEL) {
    int lane = threadIdx.x & 63;
    int wv = (blockIdx.x * blockDim.x + threadIdx.x) >> 6;
    if (wv >= NSEL) return;
    int node = idx[wv];
    float hs = lrelu(agg[(size_t)node * 64 + lane] + b1[lane]);
    out[(size_t)wv * 64 + lane] = hs;
#pragma unroll
    for (int o = 0; o < 5; ++o) {
        float p = hs * Wm[lane * 5 + o];
#pragma unroll
        for (int offs = 32; offs > 0; offs >>= 1) p += __shfl_down(p, offs);
        if (lane == 0)
            out[(size_t)NSEL * 64 + (size_t)wv * 5 + o] =
                1.0f / (1.0f + expf(-(p + bm[o])));
    }
}

extern "C" void kernel_launch(void* const* d_in, const int* in_sizes, int n_in,
                              void* d_out, int out_size, void* d_ws, size_t ws_size,
                              hipStream_t stream) {
    const float* x   = (const float*)d_in[0];
    const int*   ei  = (const int*)d_in[1];
    const int*   idx = (const int*)d_in[2];
    const float* W0  = (const float*)d_in[3];
    const float* b0  = (const float*)d_in[4];
    const float* W1  = (const float*)d_in[5];
    const float* b1  = (const float*)d_in[6];
    const float* Wm  = (const float*)d_in[7];
    const float* bm  = (const float*)d_in[8];

    int N    = in_sizes[0] / 128;
    int E    = in_sizes[1] / 2;
    int NSEL = in_sizes[2];
    const int* src = ei;
    const int* dst = ei + E;

    // workspace layout (all 4-byte elems, 1024-elem aligned chunks)
    char* w = (char*)d_ws;
    size_t Na = ((size_t)N + 1023) & ~(size_t)1023;
    size_t Ea = ((size_t)E + 1023) & ~(size_t)1023;
    float* dinv    = (float*)w;                 w += Na * 4;
    int*   cnt     = (int*)w;                   w += Na * 4;
    int*   off     = (int*)w;                   w += (Na + 1024) * 4;
    int*   bsum    = (int*)w;                   w += 1024 * 4;
    int*   esorted = (int*)w;                   w += Ea * 4;
    float* buf1    = (float*)w;                 w += (size_t)N * 64 * 4;  // h_s
    float* buf2    = (float*)w;                                          // agg

    int nb = (N + 1023) / 1024;

    // CSR build + dinv
    hipMemsetAsync(cnt, 0, (size_t)N * sizeof(int), stream);
    k_hist<<<(E + 255) / 256, 256, 0, stream>>>(dst, E, cnt);
    k_dinv<<<(N + 255) / 256, 256, 0, stream>>>(cnt, dinv, N);
    k_blocksum<<<nb, 256, 0, stream>>>(cnt, N, bsum);
    k_scan_bsum<<<1, 1024, 0, stream>>>(bsum, nb, off + N);
    k_scan_block<<<nb, 256, 0, stream>>>(cnt, bsum, off, N);
    hipMemsetAsync(cnt, 0, (size_t)N * sizeof(int), stream);
    k_scatter<<<(E + 255) / 256, 256, 0, stream>>>(src, dst, off, cnt, esorted, E);

    int gemm_blocks = (N + 255) / 256;  // 4 waves/block, 64 rows/wave
    int agg_blocks  = (N + 3) / 4;      // 4 waves/block, 1 node/wave

    k_gemm<128, false><<<gemm_blocks, 256, 0, stream>>>(x, W0, nullptr, dinv, buf1, N);
    k_agg<<<agg_blocks, 256, 0, stream>>>(off, esorted, dinv, buf1, buf2, N);
    k_gemm<64, true><<<gemm_blocks, 256, 0, stream>>>(buf2, W1, b0, dinv, buf1, N);
    k_agg<<<agg_blocks, 256, 0, stream>>>(off, esorted, dinv, buf1, buf2, N);
    k_out<<<(NSEL + 3) / 4, 256, 0, stream>>>(idx, buf2, b1, Wm, bm, (float*)d_out, NSEL);
}

// Round 4
// 551.515 us; speedup vs baseline: 1.2578x; 1.2578x over previous
//
#include <hip/hip_runtime.h>
#include <math.h>

// GCN: h0 = lrelu(Agg(x@W0)+b0); h1 = lrelu(Agg(h0@W1)+b1); out = sigmoid(h1[idx]@Wm+bm)
// Agg (sym-norm + self loops): agg[d] = dinv[d] * ( sum_{e:dst=d} h_s[src] + h_s[d] ),
// with h_s = h * dinv[row] (pre-scaled in GEMM epilogue).
// Edges counting-sorted by dst into CSR once per call -> atomic-free aggregation.
// GEMM: block = 64 rows x 64 cols; wave owns 16-col slice (acc[16]/lane, lane=row);
// x chunk staged in LDS (transposed, pad 66); W via scalar loads (readfirstlane(wv)).

__device__ __forceinline__ float lrelu(float x) { return x > 0.0f ? x : 0.01f * x; }

// ---------- degree / CSR build ----------

__global__ void k_hist(const int* __restrict__ dst, int E, int* __restrict__ cnt) {
    int i = blockIdx.x * blockDim.x + threadIdx.x;
    if (i < E) atomicAdd(cnt + dst[i], 1);
}

__global__ void k_dinv(const int* __restrict__ cnt, float* __restrict__ dinv, int N) {
    int i = blockIdx.x * blockDim.x + threadIdx.x;
    if (i < N) dinv[i] = rsqrtf((float)cnt[i] + 1.0f);  // +1 self loop
}

__global__ void k_blocksum(const int* __restrict__ cnt, int N, int* __restrict__ bsum) {
    __shared__ int sm[256];
    int b = blockIdx.x, t = threadIdx.x;
    int base = b * 1024 + t * 4;
    int s = 0;
#pragma unroll
    for (int i = 0; i < 4; ++i) { int j = base + i; if (j < N) s += cnt[j]; }
    sm[t] = s; __syncthreads();
    for (int off = 128; off > 0; off >>= 1) {
        if (t < off) sm[t] += sm[t + off];
        __syncthreads();
    }
    if (t == 0) bsum[b] = sm[0];
}

__global__ void k_scan_bsum(int* __restrict__ bsum, int nb, int* __restrict__ offN) {
    __shared__ int sm[1024];
    int t = threadIdx.x;
    int v = (t < nb) ? bsum[t] : 0;
    sm[t] = v; __syncthreads();
    for (int d = 1; d < 1024; d <<= 1) {
        int add = (t >= d) ? sm[t - d] : 0;
        __syncthreads();
        sm[t] += add;
        __syncthreads();
    }
    if (t < nb) bsum[t] = sm[t] - v;       // exclusive
    if (t == nb - 1) *offN = sm[t];        // total == E -> off[N]
}

__global__ void k_scan_block(const int* __restrict__ cnt, const int* __restrict__ bsum,
                             int* __restrict__ off, int N) {
    __shared__ int sm[256];
    int b = blockIdx.x, t = threadIdx.x;
    int base = b * 1024 + t * 4;
    int v[4];
#pragma unroll
    for (int i = 0; i < 4; ++i) { int j = base + i; v[i] = (j < N) ? cnt[j] : 0; }
    int tsum = v[0] + v[1] + v[2] + v[3];
    sm[t] = tsum; __syncthreads();
    for (int d = 1; d < 256; d <<= 1) {
        int val = (t >= d) ? sm[t - d] : 0;
        __syncthreads();
        sm[t] += val;
        __syncthreads();
    }
    int run = sm[t] - tsum + bsum[b];
#pragma unroll
    for (int i = 0; i < 4; ++i) {
        int j = base + i;
        if (j < N) off[j] = run;
        run += v[i];
    }
}

__global__ void k_scatter(const int* __restrict__ src, const int* __restrict__ dst,
                          const int* __restrict__ off, int* __restrict__ cnt,
                          int* __restrict__ esorted, int E) {
    int e = blockIdx.x * blockDim.x + threadIdx.x;
    if (e < E) {
        int d = dst[e];
        int p = off[d] + atomicAdd(cnt + d, 1);
        esorted[p] = src[e];
    }
}

// ---------- GEMM ----------
// grid = ceil(N/64). Block: 64 rows x 64 cols. Wave wv -> cols [16wv,16wv+16).
// lane = row. acc[16] per lane. K chunked by 32; chunk staged transposed in LDS
// [32][66] (pad 66: writes & reads both 2-way bank-aliased = free). Double buffer.

template <int K, bool TRANS>  // TRANS: stage lrelu(v + b0[k])
__global__ __launch_bounds__(256) void k_gemm(const float* __restrict__ A,
                                              const float* __restrict__ W,
                                              const float* __restrict__ b0,
                                              const float* __restrict__ dinv,
                                              float* __restrict__ hout, int N) {
    constexpr int CH = 32, NCH = K / CH, LSTR = 66;
    __shared__ float xs[2 * CH * LSTR];
    int t = threadIdx.x;
    int lane = t & 63, wv = t >> 6;
    int wvu = __builtin_amdgcn_readfirstlane(wv);  // force wave-uniform col group
    int rowBase = blockIdx.x * 64;
    int row = rowBase + lane;

    float4 st[2];
    auto load_chunk = [&](int c) {
#pragma unroll
        for (int i = 0; i < 2; ++i) {
            int g = i * 256 + t;          // 0..511
            int r = g >> 3;               // 0..63
            int kq = g & 7;               // float4 idx in 32-k chunk
            int gr = rowBase + r; if (gr >= N) gr = N - 1;
            float4 v = *(const float4*)(A + (size_t)gr * K + c * CH + kq * 4);
            if (TRANS) {
                float4 b = *(const float4*)(b0 + c * CH + kq * 4);
                v.x = lrelu(v.x + b.x); v.y = lrelu(v.y + b.y);
                v.z = lrelu(v.z + b.z); v.w = lrelu(v.w + b.w);
            }
            st[i] = v;
        }
    };
    auto write_chunk = [&](int buf) {
        float* bb = xs + buf * (CH * LSTR);
#pragma unroll
        for (int i = 0; i < 2; ++i) {
            int g = i * 256 + t;
            int r = g >> 3, kq = g & 7;
            bb[(kq * 4 + 0) * LSTR + r] = st[i].x;
            bb[(kq * 4 + 1) * LSTR + r] = st[i].y;
            bb[(kq * 4 + 2) * LSTR + r] = st[i].z;
            bb[(kq * 4 + 3) * LSTR + r] = st[i].w;
        }
    };

    float acc[16];
#pragma unroll
    for (int c = 0; c < 16; ++c) acc[c] = 0.0f;

    load_chunk(0);
    write_chunk(0);
    __syncthreads();

    for (int c = 0; c < NCH; ++c) {
        if (c + 1 < NCH) load_chunk(c + 1);  // global loads fly over the FMAs
        const float* xb = xs + (c & 1) * (CH * LSTR) + lane;
#pragma unroll
        for (int kk = 0; kk < CH; ++kk) {
            float xv = xb[kk * LSTR];
            const float4* W4 = (const float4*)(W + (size_t)(c * CH + kk) * 64 + wvu * 16);
            float4 w0 = W4[0], w1 = W4[1], w2 = W4[2], w3 = W4[3];  // scalar loads
            acc[0]  = fmaf(xv, w0.x, acc[0]);  acc[1]  = fmaf(xv, w0.y, acc[1]);
            acc[2]  = fmaf(xv, w0.z, acc[2]);  acc[3]  = fmaf(xv, w0.w, acc[3]);
            acc[4]  = fmaf(xv, w1.x, acc[4]);  acc[5]  = fmaf(xv, w1.y, acc[5]);
            acc[6]  = fmaf(xv, w1.z, acc[6]);  acc[7]  = fmaf(xv, w1.w, acc[7]);
            acc[8]  = fmaf(xv, w2.x, acc[8]);  acc[9]  = fmaf(xv, w2.y, acc[9]);
            acc[10] = fmaf(xv, w2.z, acc[10]); acc[11] = fmaf(xv, w2.w, acc[11]);
            acc[12] = fmaf(xv, w3.x, acc[12]); acc[13] = fmaf(xv, w3.y, acc[13]);
            acc[14] = fmaf(xv, w3.z, acc[14]); acc[15] = fmaf(xv, w3.w, acc[15]);
        }
        if (c + 1 < NCH) write_chunk((c + 1) & 1);
        __syncthreads();
    }

    if (row >= N) return;
    float dv = dinv[row];
    float* o = hout + (size_t)row * 64 + wvu * 16;
#pragma unroll
    for (int q = 0; q < 4; ++q) {
        float4 v;
        v.x = acc[4 * q + 0] * dv; v.y = acc[4 * q + 1] * dv;
        v.z = acc[4 * q + 2] * dv; v.w = acc[4 * q + 3] * dv;
        *(float4*)(o + 4 * q) = v;
    }
}

// ---------- CSR aggregation: one wave per node; 2 edges per load ----------
// lane = (half, l): half-wave h reads float2 (channels 2l,2l+1) of edge stream
// t%2==h^1... half1 takes even relative edges, half0 takes odd + the self loop.

__global__ __launch_bounds__(256) void k_agg(const int* __restrict__ off,
                                             const int* __restrict__ esorted,
                                             const float* __restrict__ dinv,
                                             const float* __restrict__ hs,
                                             float* __restrict__ agg, int N) {
    int lane = threadIdx.x & 63;
    int node = (blockIdx.x * blockDim.x + threadIdx.x) >> 6;
    if (node >= N) return;
    int half = lane >> 5, l = lane & 31;
    int beg = off[node], end = off[node + 1];

    float ax = 0.0f, ay = 0.0f;
    if (half == 0) {
        float2 s = *(const float2*)(hs + (size_t)node * 64 + 2 * l);  // self loop
        ax = s.x; ay = s.y;
    }
    int j = beg + 1 - half;  // half0: odd rel idx, half1: even rel idx
    for (; j + 2 < end; j += 4) {
        int s0 = esorted[j], s1 = esorted[j + 2];
        float2 v0 = *(const float2*)(hs + (size_t)s0 * 64 + 2 * l);
        float2 v1 = *(const float2*)(hs + (size_t)s1 * 64 + 2 * l);
        ax += v0.x + v1.x; ay += v0.y + v1.y;
    }
    if (j < end) {
        int s0 = esorted[j];
        float2 v0 = *(const float2*)(hs + (size_t)s0 * 64 + 2 * l);
        ax += v0.x; ay += v0.y;
    }
    // combine the two half-wave streams
    ax += __shfl(ax, lane ^ 32);
    ay += __shfl(ay, lane ^ 32);
    if (half == 0) {
        float dv = dinv[node];
        float2 o; o.x = ax * dv; o.y = ay * dv;
        *(float2*)(agg + (size_t)node * 64 + 2 * l) = o;
    }
}

// ---------- epilogue ----------

__global__ void k_out(const int* __restrict__ idx, const float* __restrict__ agg,
                      const float* __restrict__ b1, const float* __restrict__ Wm,
                      const float* __restrict__ bm, float* __restrict__ out, int NSEL) {
    int lane = threadIdx.x & 63;
    int wv = (blockIdx.x * blockDim.x + threadIdx.x) >> 6;
    if (wv >= NSEL) return;
    int node = idx[wv];
    float hs = lrelu(agg[(size_t)node * 64 + lane] + b1[lane]);
    out[(size_t)wv * 64 + lane] = hs;
#pragma unroll
    for (int o = 0; o < 5; ++o) {
        float p = hs * Wm[lane * 5 + o];
#pragma unroll
        for (int offs = 32; offs > 0; offs >>= 1) p += __shfl_down(p, offs);
        if (lane == 0)
            out[(size_t)NSEL * 64 + (size_t)wv * 5 + o] =
                1.0f / (1.0f + expf(-(p + bm[o])));
    }
}

extern "C" void kernel_launch(void* const* d_in, const int* in_sizes, int n_in,
                              void* d_out, int out_size, void* d_ws, size_t ws_size,
                              hipStream_t stream) {
    const float* x   = (const float*)d_in[0];
    const int*   ei  = (const int*)d_in[1];
    const int*   idx = (const int*)d_in[2];
    const float* W0  = (const float*)d_in[3];
    const float* b0  = (const float*)d_in[4];
    const float* W1  = (const float*)d_in[5];
    const float* b1  = (const float*)d_in[6];
    const float* Wm  = (const float*)d_in[7];
    const float* bm  = (const float*)d_in[8];

    int N    = in_sizes[0] / 128;
    int E    = in_sizes[1] / 2;
    int NSEL = in_sizes[2];
    const int* src = ei;
    const int* dst = ei + E;

    char* w = (char*)d_ws;
    size_t Na = ((size_t)N + 1023) & ~(size_t)1023;
    size_t Ea = ((size_t)E + 1023) & ~(size_t)1023;
    float* dinv    = (float*)w;                 w += Na * 4;
    int*   cnt     = (int*)w;                   w += Na * 4;
    int*   off     = (int*)w;                   w += (Na + 1024) * 4;
    int*   bsum    = (int*)w;                   w += 1024 * 4;
    int*   esorted = (int*)w;                   w += Ea * 4;
    float* buf1    = (float*)w;                 w += (size_t)N * 64 * 4;  // h_s
    float* buf2    = (float*)w;                                          // agg

    int nb = (N + 1023) / 1024;

    hipMemsetAsync(cnt, 0, (size_t)N * sizeof(int), stream);
    k_hist<<<(E + 255) / 256, 256, 0, stream>>>(dst, E, cnt);
    k_dinv<<<(N + 255) / 256, 256, 0, stream>>>(cnt, dinv, N);
    k_blocksum<<<nb, 256, 0, stream>>>(cnt, N, bsum);
    k_scan_bsum<<<1, 1024, 0, stream>>>(bsum, nb, off + N);
    k_scan_block<<<nb, 256, 0, stream>>>(cnt, bsum, off, N);
    hipMemsetAsync(cnt, 0, (size_t)N * sizeof(int), stream);
    k_scatter<<<(E + 255) / 256, 256, 0, stream>>>(src, dst, off, cnt, esorted, E);

    int gemm_blocks = (N + 63) / 64;   // 64 rows/block, 4 waves share them
    int agg_blocks  = (N + 3) / 4;     // 1 node/wave

    k_gemm<128, false><<<gemm_blocks, 256, 0, stream>>>(x, W0, nullptr, dinv, buf1, N);
    k_agg<<<agg_blocks, 256, 0, stream>>>(off, esorted, dinv, buf1, buf2, N);
    k_gemm<64, true><<<gemm_blocks, 256, 0, stream>>>(buf2, W1, b0, dinv, buf1, N);
    k_agg<<<agg_blocks, 256, 0, stream>>>(off, esorted, dinv, buf1, buf2, N);
    k_out<<<(NSEL + 3) / 4, 256, 0, stream>>>(idx, buf2, b1, Wm, bm, (float*)d_out, NSEL);
}